// Round 2
// baseline (15188.687 us; speedup 1.0000x reference)
//
#include <hip/hip_runtime.h>
#include <math.h>

#define T_LEN 2048
#define B_SZ  32
#define D_IN  128
#define U_SZ  512
#define N_SZ  256
#define GS    64
#define NT    512

// workspace offsets (in floats)
constexpr size_t OFF_AM  = 0;                                  // Am [256][256]
constexpr size_t OFF_WMM = OFF_AM  + (size_t)N_SZ*N_SZ;        // Wmm [256][512]
constexpr size_t OFF_BW  = OFF_WMM + (size_t)N_SZ*U_SZ;        // bw [512]
constexpr size_t OFF_UX  = OFF_BW  + U_SZ;                     // ux [2048][32]
constexpr size_t OFF_XT  = OFF_UX  + (size_t)T_LEN*B_SZ;       // xT [2048][128][32]
constexpr size_t OFF_S   = OFF_XT  + (size_t)T_LEN*D_IN*B_SZ;  // S [2][768][32]
constexpr size_t OFF_FLG = OFF_S   + (size_t)2*768*B_SZ;       // flags [2][64][16]

#define FMA4(A, S0, W0) \
  A.x = fmaf(S0, W0.x, A.x); A.y = fmaf(S0, W0.y, A.y); \
  A.z = fmaf(S0, W0.z, A.z); A.w = fmaf(S0, W0.w, A.w);
#define FMA2(A, S0, W0) \
  A.x = fmaf(S0, W0.x, A.x); A.y = fmaf(S0, W0.y, A.y);

// ---- fence-free cross-XCD primitives: sc1 (agent-scope) ops bypass the
// non-coherent per-XCD L2 and are served at the device coherence point ----
__device__ inline float2 ld_agent_f2(const float* p) {
  unsigned long long v = __hip_atomic_load((const unsigned long long*)p,
                                           __ATOMIC_RELAXED, __HIP_MEMORY_SCOPE_AGENT);
  union { unsigned long long u; float2 f; } c; c.u = v; return c.f;
}
__device__ inline void st_agent_f1(float* p, float f) {
  union { float f; unsigned u; } c; c.f = f;
  __hip_atomic_store((unsigned*)p, c.u, __ATOMIC_RELAXED, __HIP_MEMORY_SCOPE_AGENT);
}

// Am[k][j] = AT[k][j] + I + me[k]*BT[j]   (folds m@me term of u into m-recurrence)
__global__ void k_am(const float* __restrict__ AT, const float* __restrict__ me,
                     const float* __restrict__ BT, float* __restrict__ ws) {
  int k = blockIdx.x, j = threadIdx.x;
  float v = AT[(size_t)k*N_SZ + j] + (k == j ? 1.0f : 0.0f) + me[k]*BT[j];
  ws[OFF_AM + (size_t)k*N_SZ + j] = v;
}

// bw[j] = sum_q BT[q]*Wm[q][j]
__global__ void k_bw(const float* __restrict__ BT, const float* __restrict__ Wm,
                     float* __restrict__ ws) {
  int j = blockIdx.x*256 + threadIdx.x;
  float acc = 0.f;
  for (int q = 0; q < N_SZ; ++q) acc += BT[q]*Wm[(size_t)q*U_SZ + j];
  ws[OFF_BW + j] = acc;
}

// Wmm = Am @ Wm   [256][512]
__global__ void k_wmm(const float* __restrict__ Wm, float* __restrict__ ws) {
  __shared__ float amr[N_SZ];
  int k = blockIdx.x, tid = threadIdx.x;
  amr[tid] = ws[OFF_AM + (size_t)k*N_SZ + tid];
  __syncthreads();
  float acc0 = 0.f, acc1 = 0.f;
  for (int q = 0; q < N_SZ; ++q) {
    float a = amr[q];
    acc0 += a * Wm[(size_t)q*U_SZ + tid];
    acc1 += a * Wm[(size_t)q*U_SZ + tid + 256];
  }
  ws[OFF_WMM + (size_t)k*U_SZ + tid]       = acc0;
  ws[OFF_WMM + (size_t)k*U_SZ + tid + 256] = acc1;
}

// ux[t][b] = x[b][t][:] . ie
__global__ void k_ux(const float* __restrict__ x, const float* __restrict__ ie,
                     float* __restrict__ ws) {
  __shared__ __align__(16) float iel[D_IN];
  __shared__ float red[B_SZ*9];
  int t = blockIdx.x, tid = threadIdx.x;
  if (tid < D_IN) iel[tid] = ie[tid];
  __syncthreads();
  int b = tid >> 3, p = tid & 7;
  const float4* xr = (const float4*)(x + ((size_t)b*T_LEN + t)*D_IN);
  const float4* wr = (const float4*)iel;
  float s = 0.f;
  for (int q = 0; q < 4; ++q) {
    int fi = p + q*8;
    float4 v = xr[fi];
    float4 w = wr[fi];
    s += v.x*w.x + v.y*w.y + v.z*w.z + v.w*w.w;
  }
  red[b*9 + p] = s;
  __syncthreads();
  if (tid < B_SZ) {
    float acc = 0.f;
    for (int p2 = 0; p2 < 8; ++p2) acc += red[tid*9 + p2];
    ws[OFF_UX + (size_t)t*B_SZ + tid] = acc;
  }
}

// xT[t][d][b] = x[b][t][d]
__global__ void k_xt(const float* __restrict__ x, float* __restrict__ ws) {
  __shared__ float tile[B_SZ*33];
  int bid = blockIdx.x;
  int t = bid >> 2, d0 = (bid & 3)*32;
  int tid = threadIdx.x;
  int lo = tid & 31, hi = tid >> 5;
  for (int p = 0; p < 4; ++p) {
    int b = hi + p*8;
    tile[b*33 + lo] = x[((size_t)b*T_LEN + t)*D_IN + d0 + lo];
  }
  __syncthreads();
  float* dst = ws + OFF_XT + ((size_t)t*D_IN + d0)*B_SZ;
  for (int p = 0; p < 4; ++p) {
    int d = hi + p*8;
    dst[(size_t)d*B_SZ + lo] = tile[lo*33 + d];
  }
}

// init: S[0] = [h0 | m0] in [k][b]; zero the barrier flags (both groups)
__global__ void k_init(const float* __restrict__ h0, const float* __restrict__ mm0,
                       float* __restrict__ ws) {
  int bid = blockIdx.x, tid = threadIdx.x;
  if (bid < 24) {
    for (int i = 0; i < 4; ++i) {
      int e = bid*1024 + i*256 + tid;
      int k = e >> 5, b = e & 31;
      float v = (k < U_SZ) ? h0[(size_t)b*U_SZ + k] : mm0[(size_t)b*N_SZ + (k - U_SZ)];
      ws[OFF_S + e] = v;
    }
  } else {
    for (int idx = tid; idx < 2*GS*16; idx += 256) ws[OFF_FLG + idx] = 0.0f;  // 0u bits
  }
}

// persistent scan, batch-group-pipelined: the 32 batches are 2 independent
// recurrence groups of 16 (weights shared). Per step we run chunk A (b 0-15)
// then chunk B (b 16-31); each group's cross-XCD exchange latency (store
// drain -> flag -> remote poll -> agent loads) hides under the other group's
// compute chunk. Protocol per chunk is identical to the proven single-group
// one: stores -> syncthreads(vmcnt0) -> epoch flag -> poll in shadow.
__global__ __launch_bounds__(NT, 2) void k_scan(
    const float* __restrict__ Wh, const float* __restrict__ Wi,
    const float* __restrict__ he, const float* __restrict__ btv,
    float* __restrict__ ws, float* __restrict__ out)
{
  const int g = blockIdx.x, tid = threadIdx.x;
  const int JH = g*8, JM = g*4;
  const int bt = tid & 3, jt = (tid >> 2) & 1, ks = tid >> 3;   // ks in [0,64)
  const int b0 = bt*4;

  float* uxw = ws + OFF_UX;
  float* xT  = ws + OFF_XT;
  float* Sb  = ws + OFF_S;
  unsigned* flags = (unsigned*)(ws + OFF_FLG);

  __shared__ __align__(16) float Wl[896*8];   // [k][jj]: k<512 Wh, <768 Wmm, <896 Wi
  __shared__ __align__(16) float Aml[N_SZ*4]; // [k][jj] m-columns of Am
  __shared__ float Hl[U_SZ];                  // hidden_encoders
  __shared__ float redh[NT*17];
  __shared__ float redm[NT*9];
  __shared__ float reds[256*9];
  __shared__ float bwl[8], btl[4];

  for (int idx = tid; idx < 896*8; idx += NT) {
    int k = idx >> 3, jj = idx & 7;
    float v;
    if (k < 512)      v = Wh[(size_t)k*U_SZ + JH + jj];
    else if (k < 768) v = ws[OFF_WMM + (size_t)(k-512)*U_SZ + JH + jj];
    else              v = Wi[(size_t)(k-768)*U_SZ + JH + jj];
    Wl[idx] = v;
  }
  for (int idx = tid; idx < N_SZ*4; idx += NT) {
    int k = idx >> 2, jj = idx & 3;
    Aml[idx] = ws[OFF_AM + (size_t)k*N_SZ + JM + jj];
  }
  for (int idx = tid; idx < U_SZ; idx += NT) Hl[idx] = he[idx];
  if (tid < 8) bwl[tid] = ws[OFF_BW + JH + tid];
  if (tid < 4) btl[tid] = btv[JM + tid];
  __syncthreads();

  const float4* Wl4  = (const float4*)Wl;
  const float2* Aml2 = (const float2*)Aml;

  float4 a0={0,0,0,0}, a1={0,0,0,0}, a2={0,0,0,0}, a3={0,0,0,0};
  // seg3 for chunk (t=0, group A): x_0 @ Wi, local data only
  {
    const float* xrow = xT;
    #pragma unroll
    for (int i = 0; i < 2; ++i) {
      int kk = 768 + i*64 + ks;
      float4 sv = *(const float4*)(xrow + (size_t)(kk - 768)*B_SZ + b0);
      float4 wv = Wl4[kk*2 + jt];
      FMA4(a0, sv.x, wv) FMA4(a1, sv.y, wv) FMA4(a2, sv.z, wv) FMA4(a3, sv.w, wv)
    }
  }

  for (int cc = 0; cc < 2*T_LEN; ++cc) {
    const int t = cc >> 1, c = cc & 1, g16 = c << 4;
    const float* S  = Sb + (size_t)(t & 1)*(768*B_SZ);
    float*       Sn = Sb + (size_t)((t+1) & 1)*(768*B_SZ);
    const int boff = g16 + b0;

    float uxv = uxw[(size_t)t*B_SZ + g16 + (tid & 15)];

    float2 q0={0,0}, q1={0,0}, q2={0,0}, q3={0,0};
    float4 sa={0,0,0,0};

    // seg1: k in [0,512): h x Wh (+ local s-partial h.he)
    #pragma unroll
    for (int i = 0; i < 8; ++i) {
      int kk = i*64 + ks;
      const float* sp0 = S + (size_t)kk*B_SZ + boff;
      float2 s01 = ld_agent_f2(sp0);
      float2 s23 = ld_agent_f2(sp0 + 2);
      float4 wv = Wl4[kk*2 + jt];
      float hv = Hl[kk];
      FMA4(a0, s01.x, wv) FMA4(a1, s01.y, wv) FMA4(a2, s23.x, wv) FMA4(a3, s23.y, wv)
      sa.x = fmaf(s01.x, hv, sa.x); sa.y = fmaf(s01.y, hv, sa.y);
      sa.z = fmaf(s23.x, hv, sa.z); sa.w = fmaf(s23.y, hv, sa.w);
    }
    // seg2: k in [512,768): m x Wmm  +  m x Am (m-cols split across jt)
    #pragma unroll
    for (int i = 0; i < 4; ++i) {
      int kk = 512 + i*64 + ks;
      const float* sp0 = S + (size_t)kk*B_SZ + boff;
      float2 s01 = ld_agent_f2(sp0);
      float2 s23 = ld_agent_f2(sp0 + 2);
      float4 wv = Wl4[kk*2 + jt];
      FMA4(a0, s01.x, wv) FMA4(a1, s01.y, wv) FMA4(a2, s23.x, wv) FMA4(a3, s23.y, wv)
      float2 av = Aml2[(kk - 512)*2 + jt];
      FMA2(q0, s01.x, av) FMA2(q1, s01.y, av) FMA2(q2, s23.x, av) FMA2(q3, s23.y, av)
    }

    // partials to LDS
    {
      float* rp = redh + tid*17;
      rp[0]=a0.x;  rp[1]=a0.y;  rp[2]=a0.z;  rp[3]=a0.w;
      rp[4]=a1.x;  rp[5]=a1.y;  rp[6]=a1.z;  rp[7]=a1.w;
      rp[8]=a2.x;  rp[9]=a2.y;  rp[10]=a2.z; rp[11]=a2.w;
      rp[12]=a3.x; rp[13]=a3.y; rp[14]=a3.z; rp[15]=a3.w;
      float* rm = redm + tid*9;
      rm[0]=q0.x; rm[1]=q0.y; rm[2]=q1.x; rm[3]=q1.y;
      rm[4]=q2.x; rm[5]=q2.y; rm[6]=q3.x; rm[7]=q3.y;
      if (jt == 0) {
        float* rs = reds + (bt + 4*ks)*9;
        rs[0]=sa.x; rs[1]=sa.y; rs[2]=sa.z; rs[3]=sa.w;
      }
    }
    __syncthreads();   // (A)

    // epilogue: tid<128 -> h-cols (be,je); tid in [128,192) -> m-cols (be,jm)
    float val = 0.f;
    if (tid < 192) {
      const int be2 = tid & 15, btb = be2 >> 2, xx = be2 & 3;
      float ssb = uxv;
      #pragma unroll
      for (int k2 = 0; k2 < 64; ++k2) ssb += reds[(btb + 4*k2)*9 + xx];
      if (tid < 128) {
        const int je = tid >> 4, jt2 = je >> 2, yy = je & 3;
        float sum = 0.f;
        #pragma unroll
        for (int k2 = 0; k2 < 64; ++k2)
          sum += redh[(btb + 4*jt2 + 8*k2)*17 + xx*4 + yy];
        val = tanhf(sum + ssb*bwl[je]);
        st_agent_f1(Sn + (size_t)(JH + je)*B_SZ + g16 + be2, val);
      } else {
        const int jm = (tid - 128) >> 4;
        const int jtm = jm >> 1, jc = jm & 1;
        float sum = 0.f;
        #pragma unroll
        for (int k2 = 0; k2 < 64; ++k2)
          sum += redm[(btb + 4*jtm + 8*k2)*9 + xx*2 + jc];
        sum += ssb*btl[jm];
        st_agent_f1(Sn + (size_t)(512 + JM + jm)*B_SZ + g16 + be2, sum);
      }
    }
    __syncthreads();   // (B) — implicit vmcnt(0): all Sn sc1 stores are at IC

    // arrival flag ASAP, then off-critical-path work in the barrier shadow
    const int cn = cc + 1, t2 = cn >> 1, c2 = cn & 1;
    if (t + 1 < T_LEN && tid == 0)
      __hip_atomic_store(flags + ((size_t)c*GS + g)*16, (unsigned)(t + 1),
                         __ATOMIC_RELAXED, __HIP_MEMORY_SCOPE_AGENT);
    if (tid < 128)
      out[((size_t)(g16 + (tid & 15))*T_LEN + t)*U_SZ + JH + (tid >> 4)] = val;

    a0.x=a0.y=a0.z=a0.w=0.f; a1=a0; a2=a0; a3=a0;
    if (cn < 2*T_LEN) {
      // seg3 prefetch for next chunk (x @ Wi, local data), then poll the
      // next chunk's group flags — both in the shadow of this chunk's exchange
      const int g16n = c2 << 4;
      const float* xrow = xT + (size_t)t2*D_IN*B_SZ;
      #pragma unroll
      for (int i = 0; i < 2; ++i) {
        int kk = 768 + i*64 + ks;
        float4 sv = *(const float4*)(xrow + (size_t)(kk - 768)*B_SZ + g16n + b0);
        float4 wv = Wl4[kk*2 + jt];
        FMA4(a0, sv.x, wv) FMA4(a1, sv.y, wv) FMA4(a2, sv.z, wv) FMA4(a3, sv.w, wv)
      }
      if (tid < GS) {
        const unsigned* fp = flags + ((size_t)c2*GS + tid)*16;
        while (__hip_atomic_load(fp, __ATOMIC_RELAXED, __HIP_MEMORY_SCOPE_AGENT)
               < (unsigned)t2) { }
      }
    }
    __syncthreads();   // (C)
  }
}

extern "C" void kernel_launch(void* const* d_in, const int* in_sizes, int n_in,
                              void* d_out, int out_size, void* d_ws, size_t ws_size,
                              hipStream_t stream) {
  const float* x   = (const float*)d_in[0];
  const float* h0  = (const float*)d_in[1];
  const float* m0  = (const float*)d_in[2];
  const float* ie  = (const float*)d_in[3];
  const float* he  = (const float*)d_in[4];
  const float* me  = (const float*)d_in[5];
  const float* Wi  = (const float*)d_in[6];
  const float* Wh  = (const float*)d_in[7];
  const float* Wm  = (const float*)d_in[8];
  const float* AT  = (const float*)d_in[9];
  const float* BT  = (const float*)d_in[10];
  float* ws  = (float*)d_ws;
  float* out = (float*)d_out;

  k_am  <<<N_SZ, 256, 0, stream>>>(AT, me, BT, ws);
  k_bw  <<<2, 256, 0, stream>>>(BT, Wm, ws);
  k_wmm <<<N_SZ, 256, 0, stream>>>(Wm, ws);
  k_ux  <<<T_LEN, 256, 0, stream>>>(x, ie, ws);
  k_xt  <<<T_LEN*4, 256, 0, stream>>>(x, ws);
  k_init<<<25, 256, 0, stream>>>(h0, m0, ws);
  k_scan<<<GS, NT, 0, stream>>>(Wh, Wi, he, BT, ws, out);
}